// Round 12
// baseline (104.325 us; speedup 1.0000x reference)
//
#include <hip/hip_runtime.h>
#include <hip/hip_bf16.h>

// out[b,d,r] = sum_c p[b,c] * softmax_d( x[b,:] @ W[:, c*8+d, r] + bias[c,d,r] )
// B=16384, F=128, C=8, R=64.  bf16 MFMA 16x16x32, fully fused.
//
// R21->R22: R18/R21 run at the SUM of their pipes (LDS 6.2k + MFMA 2.5k +
// VALU 1.0k = 9.7kcyc/c ~= measured 33us), not the max (20.5us): the per-c
// barrier re-aligns all 16 waves/CU into lockstep {read-burst -> MFMA ->
// softmax} phases, so the LDS pipe surges then idles 8x.  R22 breaks the
// lockstep with 2-c barrier WINDOWS:
//  - 1024-thr/16-wave blocks, grid 256 = exactly 1 block/CU (16 waves/CU
//    unchanged); ring-4 x 32KB = 128KB LDS (gfx950 LDS max is 160KB).
//  - per window: ONE barrier -> stage(c+2),(c+3) -> compute(c),(c+1).
//    Waves free-run ~20kcyc between barriers -> natural de-phasing lets
//    one wave's MFMA/softmax overlap another's ds_reads; barrier drains
//    halve (4 instead of 8).
// Math & per-c body R21-verbatim: d-outer MFMA (8 independent chains),
// exp2 fused per-d (LOG2E pre-folded in prepass), biasT C-in (2 f32x4),
// in-lane softmax (zero shuffles), w-major grid (XCD = blk%8 uniform in w),
// full 64B-line nontemporal stores.

#define F_DIM    128
#define NCOL     4096      // C*C*R
#define OUT_STRIDE 512     // C*R
#define LOG2E    1.44269504088896340736f

typedef __bf16 bf16x8 __attribute__((ext_vector_type(8)));
typedef float  f32x4  __attribute__((ext_vector_type(4)));

#define AS1(p) ((const __attribute__((address_space(1))) unsigned int*)(p))
#define AS3(p) ((__attribute__((address_space(3))) unsigned int*)(p))

// ---------------------------------------------------------------------------
// Prepass (R18-verbatim): W fp32 (128 x 4096 row-major) -> bf16 MFMA
// B-fragments, PRE-SCALED by log2(e).  Tile t = (c*8+d)*4 + w covers cols
// t*16..t*16+16; fragment (t,kk) holds k = kk*32 + (lane>>4)*8 + j,
// n = t*16 + (lane&15), at wf[(t*4+kk)*512].
// Also emits biasT[(c*64 + r)*8 + d] = bias[c][d][r] * log2e  (16 KB).
// ---------------------------------------------------------------------------
__global__ void wconv_kernel(const float* __restrict__ W,
                             const float* __restrict__ bias,
                             __bf16* __restrict__ wf,
                             float* __restrict__ biasT) {
    int f    = blockIdx.x * 256 + threadIdx.x;  // 0..65535
    int lane = f & 63;
    int tkk  = f >> 6;
    int t    = tkk >> 2;
    int kk   = tkk & 3;
    int kbase = kk * 32 + (lane >> 4) * 8;
    int n     = t * 16 + (lane & 15);
    bf16x8 frag;
#pragma unroll
    for (int j = 0; j < 8; ++j)
        frag[j] = (__bf16)(W[(kbase + j) * NCOL + n] * LOG2E);
    *(bf16x8*)(wf + (size_t)f * 8) = frag;

    if (f < 4096) {   // biasT: [c][r][d]
        int c = f >> 9, r = (f >> 3) & 63, d = f & 7;
        biasT[f] = bias[(c * 8 + d) * 64 + r] * LOG2E;
    }
}

// ---------------------------------------------------------------------------
// Fused GEMM + bias + softmax(d) + p-contraction.
// Block: 1024 thr (16 waves), 256 batch rows, one 16-r chunk w = blk>>6.
// Wave ww owns rows b0..b0+16.  Ring-4 x 32KB staging: per c, 32 fragments;
// wave ww stages fi = 2ww, 2ww+1.  Windows of 2 c's per barrier: stage
// (c+2),(c+3) right after the barrier, then compute c and c+1 back-to-back.
// d-OUTER mfma with exp2 fused per-d; softmax in-lane; C-in = biasT.
// C/D layout: col=lane&15 -> r, row=quad*4+jj -> batch row.
// ---------------------------------------------------------------------------
__global__ __launch_bounds__(1024, 4)
void fused_kernel(const float* __restrict__ x, const float* __restrict__ p,
                  const float* __restrict__ biasT, const __bf16* __restrict__ wf,
                  float* __restrict__ out) {
    __shared__ __align__(16) char lds[131072];   // ring-4 x 32 KB

    const int lane = threadIdx.x & 63;
    const int ww   = threadIdx.x >> 6;   // wave 0..15
    const int quad = lane >> 4;
    const int l15  = lane & 15;
    const int w    = blockIdx.x >> 6;    // r-chunk 0..3 (w-major: XCD = g%8)
    const int g    = blockIdx.x & 63;    // row-group
    const int b0   = g * 256 + ww * 16;

    // fragment fi = d*4 + kk staged by wave ww: fi = 2ww, 2ww+1
    const int fi0 = ww * 2;
    const int d0s = fi0 >> 2;            // staged d
    const int kk0 = fi0 & 3;             // staged kk base (kk0, kk0+1)

    // ---- prologue: stage c=0 -> slot 0, c=1 -> slot 1 ---------------------
#pragma unroll
    for (int c = 0; c < 2; ++c) {
        char* dst = lds + c * 32768;
        const __bf16* src =
            wf + (size_t)(((c * 8 + d0s) * 4 + w) * 4 + kk0) * 512 + lane * 8;
        __builtin_amdgcn_global_load_lds(AS1(src),       AS3(dst + fi0 * 1024),       16, 0, 0);
        __builtin_amdgcn_global_load_lds(AS1(src + 512), AS3(dst + fi0 * 1024 + 1024), 16, 0, 0);
    }

    // A fragments: afr[kk][j] = x_bf16[b0+l15][kk*32 + quad*8 + j]
    bf16x8 afr[4];
    {
        const float* xr = x + (size_t)(b0 + l15) * F_DIM + quad * 8;
#pragma unroll
        for (int kk = 0; kk < 4; ++kk) {
            float4 lo = *(const float4*)(xr + kk * 32);
            float4 hi = *(const float4*)(xr + kk * 32 + 4);
            bf16x8 f;
            f[0] = (__bf16)lo.x; f[1] = (__bf16)lo.y;
            f[2] = (__bf16)lo.z; f[3] = (__bf16)lo.w;
            f[4] = (__bf16)hi.x; f[5] = (__bf16)hi.y;
            f[6] = (__bf16)hi.z; f[7] = (__bf16)hi.w;
            afr[kk] = f;
        }
    }

    float O[8][4] = {};   // [d][jj] output accumulator over c

    // per-c compute body (slot base passed in)
    auto compute_c = [&](int c, const char* buf) {
        float pvv[4];
#pragma unroll
        for (int jj = 0; jj < 4; ++jj)
            pvv[jj] = p[(size_t)(b0 + quad * 4 + jj) * 8 + c];

        f32x4 bv0 = *(const f32x4*)(biasT + (c * 64 + w * 16 + l15) * 8);
        f32x4 bv1 = *(const f32x4*)(biasT + (c * 64 + w * 16 + l15) * 8 + 4);

        f32x4 acc[8];
#pragma unroll
        for (int d = 0; d < 8; ++d) {
            float bvd = (d < 4) ? bv0[d & 3] : bv1[d & 3];
            f32x4 a = {bvd, bvd, bvd, bvd};   // C-in = bias (row-invariant)
#pragma unroll
            for (int kk = 0; kk < 4; ++kk) {
                bf16x8 bfr = *(const bf16x8*)(buf + (d * 4 + kk) * 1024 + lane * 16);
                a = __builtin_amdgcn_mfma_f32_16x16x32_bf16(afr[kk], bfr, a, 0, 0, 0);
            }
#pragma unroll
            for (int jj = 0; jj < 4; ++jj)
                a[jj] = __builtin_amdgcn_exp2f(a[jj]);
            acc[d] = a;
        }

#pragma unroll
        for (int jj = 0; jj < 4; ++jj) {
            float s01 = acc[0][jj] + acc[1][jj], s23 = acc[2][jj] + acc[3][jj];
            float s45 = acc[4][jj] + acc[5][jj], s67 = acc[6][jj] + acc[7][jj];
            float s = (s01 + s23) + (s45 + s67);
            float scale = pvv[jj] * __builtin_amdgcn_rcpf(s);
#pragma unroll
            for (int d = 0; d < 8; ++d)
                O[d][jj] = __builtin_fmaf(acc[d][jj], scale, O[d][jj]);
        }
    };

#pragma unroll 1
    for (int wi = 0; wi < 4; ++wi) {
        const int c0 = wi * 2;
        // barrier: stages for c0, c0+1 landed (issued a full window ago,
        // implicit vmcnt(0)) AND all waves done reading slots (c0+2)&3,
        // (c0+3)&3 from the previous window.
        __syncthreads();

        // ---- issue stage(c0+2), (c0+3) into their ring slots --------------
        if (wi < 3) {
#pragma unroll
            for (int u = 2; u < 4; ++u) {
                int c = c0 + u;
                char* dst = lds + (c & 3) * 32768;
                const __bf16* src =
                    wf + (size_t)(((c * 8 + d0s) * 4 + w) * 4 + kk0) * 512 + lane * 8;
                __builtin_amdgcn_global_load_lds(AS1(src),       AS3(dst + fi0 * 1024),        16, 0, 0);
                __builtin_amdgcn_global_load_lds(AS1(src + 512), AS3(dst + fi0 * 1024 + 1024), 16, 0, 0);
            }
        }

        // ---- compute the window's two c's back-to-back (no barrier between)
        compute_c(c0,     lds + (c0 & 3) * 32768);
        compute_c(c0 + 1, lds + ((c0 + 1) & 3) * 32768);
    }

    // ---- stores: out[b, d*64 + w*16 + l15] — 64B per quad, nontemporal ----
#pragma unroll
    for (int jj = 0; jj < 4; ++jj) {
        float* orow = out + (size_t)(b0 + quad * 4 + jj) * OUT_STRIDE + w * 16 + l15;
#pragma unroll
        for (int d = 0; d < 8; ++d)
            __builtin_nontemporal_store(O[d][jj], orow + d * 64);
    }
}

extern "C" void kernel_launch(void* const* d_in, const int* in_sizes, int n_in,
                              void* d_out, int out_size, void* d_ws, size_t ws_size,
                              hipStream_t stream) {
    const float* x    = (const float*)d_in[0];   // (16384, 128)
    const float* p    = (const float*)d_in[1];   // (16384, 8)
    const float* W    = (const float*)d_in[2];   // (128, 64, 64)
    const float* bias = (const float*)d_in[3];   // (8, 8, 64)
    float* out = (float*)d_out;                  // (16384, 8, 64)
    __bf16* wf    = (__bf16*)d_ws;               // 1 MB bf16 fragments
    float*  biasT = (float*)((char*)d_ws + (1 << 20));  // 16 KB scaled bias

    wconv_kernel<<<dim3(256), dim3(256), 0, stream>>>(W, bias, wf, biasT);
    fused_kernel<<<dim3(256), dim3(1024), 0, stream>>>(x, p, biasT, wf, out);
}